// Round 1
// baseline (367.826 us; speedup 1.0000x reference)
//
#include <hip/hip_runtime.h>

using bf16x8 = __attribute__((ext_vector_type(8))) __bf16;
using f32x4  = __attribute__((ext_vector_type(4))) float;

__device__ __forceinline__ unsigned short f2bf(float f) {
  unsigned u = __builtin_bit_cast(unsigned, f);
  u += 0x7fffu + ((u >> 16) & 1u);
  return (unsigned short)(u >> 16);
}

// ---------------- fp32 -> bf16 convert ----------------
__global__ void cvt_bf16_kernel(const float* __restrict__ in,
                                unsigned short* __restrict__ out, int n) {
  int i = (blockIdx.x * blockDim.x + threadIdx.x) * 4;
  if (i < n) {
    float4 f = *(const float4*)(in + i);
    ushort4 o;
    o.x = f2bf(f.x); o.y = f2bf(f.y); o.z = f2bf(f.z); o.w = f2bf(f.w);
    *(ushort4*)(out + i) = o;
  }
}

// ---------------- transpose + convert: W[K][N] fp32 -> WT[N][K] bf16 ----------------
__global__ void transpose_cvt_kernel(const float* __restrict__ W,
                                     unsigned short* __restrict__ WT, int K, int N) {
  __shared__ float tile[32][33];
  int n0 = blockIdx.x * 32, k0 = blockIdx.y * 32;
  int tx = threadIdx.x, ty = threadIdx.y;
  #pragma unroll
  for (int i = 0; i < 32; i += 8)
    tile[ty + i][tx] = W[(size_t)(k0 + ty + i) * N + (n0 + tx)];
  __syncthreads();
  #pragma unroll
  for (int i = 0; i < 32; i += 8)
    WT[(size_t)(n0 + ty + i) * K + (k0 + tx)] = f2bf(tile[tx][ty + i]);
}

// ---------------- bf16 GEMM: C[M][N] = A[M][K] * BT[N][K]^T ----------------
// MODE 0: scatter-store bf16 into q/k/v [bh][t][d] head-major layout
// MODE 1: plain fp32 store to Cout[M][N]
template <int MODE>
__global__ __launch_bounds__(256, 2)
void gemm_bf16(const unsigned short* __restrict__ A,
               const unsigned short* __restrict__ BT,
               float* __restrict__ Cout, int K,
               unsigned short* __restrict__ q_out,
               unsigned short* __restrict__ k_out,
               unsigned short* __restrict__ v_out, int N) {
  __shared__ alignas(16) char As[128 * 32 * 2];
  __shared__ alignas(16) char Bs[128 * 32 * 2];
  const int tid = threadIdx.x;
  const int lane = tid & 63, w = tid >> 6;
  const int wm = w >> 1, wn = w & 1;
  const int l15 = lane & 15, l4 = lane >> 4;
  const int bm = blockIdx.y, bn = blockIdx.x;

  f32x4 acc[4][4] = {};

  for (int kt = 0; kt < K; kt += 32) {
    #pragma unroll
    for (int i = 0; i < 2; i++) {
      int c = tid + i * 256;
      int row = c >> 2, kc = c & 3;
      int4 av = *(const int4*)(A + (size_t)(bm * 128 + row) * K + kt + kc * 8);
      *(int4*)(As + row * 64 + ((kc ^ (row & 3)) << 4)) = av;
      int4 bv = *(const int4*)(BT + (size_t)(bn * 128 + row) * K + kt + kc * 8);
      *(int4*)(Bs + row * 64 + ((kc ^ (row & 3)) << 4)) = bv;
    }
    __syncthreads();
    bf16x8 af[4], bfr[4];
    #pragma unroll
    for (int mc = 0; mc < 4; mc++) {
      int row = wm * 64 + mc * 16 + l15;
      af[mc] = *(const bf16x8*)(As + row * 64 + ((l4 ^ (row & 3)) << 4));
    }
    #pragma unroll
    for (int nc = 0; nc < 4; nc++) {
      int row = wn * 64 + nc * 16 + l15;
      bfr[nc] = *(const bf16x8*)(Bs + row * 64 + ((l4 ^ (row & 3)) << 4));
    }
    #pragma unroll
    for (int mc = 0; mc < 4; mc++)
      #pragma unroll
      for (int nc = 0; nc < 4; nc++)
        acc[mc][nc] = __builtin_amdgcn_mfma_f32_16x16x32_bf16(af[mc], bfr[nc], acc[mc][nc], 0, 0, 0);
    __syncthreads();
  }

  #pragma unroll
  for (int mc = 0; mc < 4; mc++) {
    #pragma unroll
    for (int nc = 0; nc < 4; nc++) {
      #pragma unroll
      for (int r = 0; r < 4; r++) {
        int m = bm * 128 + wm * 64 + mc * 16 + l4 * 4 + r;
        int n = bn * 128 + wn * 64 + nc * 16 + l15;
        float val = acc[mc][nc][r];
        if (MODE == 0) {
          int b = m >> 11, t = m & 2047;
          int which = n >> 10, h = (n >> 6) & 15, d = n & 63;
          unsigned short* dst = (which == 0) ? q_out : (which == 1) ? k_out : v_out;
          dst[(((size_t)(b * 16 + h)) * 2048 + t) * 64 + d] = f2bf(val);
        } else {
          Cout[(size_t)m * N + n] = val;
        }
      }
    }
  }
}

// ---------------- flash attention: causal, B*H=64 blocks.y, 32 q-tiles blocks.x ----------------
__global__ __launch_bounds__(256, 2)
void attn_kernel(const unsigned short* __restrict__ q,
                 const unsigned short* __restrict__ k,
                 const unsigned short* __restrict__ v,
                 unsigned short* __restrict__ att) {
  __shared__ alignas(16) char Ks[64 * 128];   // K tile [64 keys][64 d] bf16, swizzled
  __shared__ alignas(16) char Vt[64 * 128];   // V^T tile [64 d][64 keys] bf16, swizzled
  __shared__ alignas(16) char Ps[4 * 16 * 128]; // per-wave P [16 q][64 keys] bf16, swizzled

  const int qt = blockIdx.x, bh = blockIdx.y;
  const int tid = threadIdx.x;
  const int lane = tid & 63, w = tid >> 6;
  const int l15 = lane & 15, l4 = lane >> 4;
  const size_t base = (size_t)bh * 2048 * 64;

  // Q fragments (A-operand): row = w*16 + l15, k-dim chunks of 8
  bf16x8 qf[2];
  {
    int qrow = qt * 64 + w * 16 + l15;
    #pragma unroll
    for (int kk = 0; kk < 2; kk++)
      qf[kk] = *(const bf16x8*)(q + base + (size_t)qrow * 64 + kk * 32 + l4 * 8);
  }

  f32x4 o[4] = {};
  float mrow[4], lrow[4];
  #pragma unroll
  for (int r = 0; r < 4; r++) { mrow[r] = -1e30f; lrow[r] = 0.f; }
  char* pbase = Ps + w * 2048;

  const float SC = 0.125f;               // 1/sqrt(64)
  const float L2E = 1.44269504088896f;   // log2(e)

  for (int kt = 0; kt <= qt; kt++) {
    // ---- stage K tile (swizzled rows) ----
    #pragma unroll
    for (int i = 0; i < 2; i++) {
      int c = tid + i * 256;
      int r = c >> 3, cc = c & 7;
      int4 kv = *(const int4*)(k + base + (size_t)(kt * 64 + r) * 64 + cc * 8);
      *(int4*)(Ks + r * 128 + ((cc ^ (r & 7)) << 4)) = kv;
    }
    // ---- stage V transposed (swizzled rows of V^T) ----
    {
      int kp = tid & 31, dc = tid >> 5;  // kp: key pair, dc: d-chunk of 8
      const unsigned short* vr = v + base + (size_t)(kt * 64 + 2 * kp) * 64 + dc * 8;
      int4 va = *(const int4*)(vr);
      int4 vb = *(const int4*)(vr + 64);
      const unsigned short* pa = (const unsigned short*)&va;
      const unsigned short* pb = (const unsigned short*)&vb;
      #pragma unroll
      for (int j = 0; j < 8; j++) {
        int d = dc * 8 + j;
        unsigned int val = ((unsigned int)pb[j] << 16) | pa[j];
        *(unsigned int*)(Vt + d * 128 + (((kp >> 2) ^ (d & 7)) << 4) + (kp & 3) * 4) = val;
      }
    }
    __syncthreads();

    // ---- S = Q K^T (per wave: 16 q rows x 64 keys) ----
    f32x4 s[4];
    #pragma unroll
    for (int nc = 0; nc < 4; nc++) {
      f32x4 accs = {};
      #pragma unroll
      for (int kk = 0; kk < 2; kk++) {
        int r = nc * 16 + l15;
        int cc = kk * 4 + l4;
        bf16x8 kf = *(const bf16x8*)(Ks + r * 128 + ((cc ^ (r & 7)) << 4));
        accs = __builtin_amdgcn_mfma_f32_16x16x32_bf16(qf[kk], kf, accs, 0, 0, 0);
      }
      s[nc] = accs;
    }

    // ---- scale + causal mask + row max ----
    const bool diag = (kt == qt);
    float rmax[4];
    #pragma unroll
    for (int r = 0; r < 4; r++) rmax[r] = -1e30f;
    #pragma unroll
    for (int nc = 0; nc < 4; nc++) {
      int key = nc * 16 + l15;
      #pragma unroll
      for (int r = 0; r < 4; r++) {
        float sv = s[nc][r] * SC;
        int row = w * 16 + l4 * 4 + r;
        if (diag && key > row) sv = -1e30f;
        s[nc][r] = sv;
        rmax[r] = fmaxf(rmax[r], sv);
      }
    }
    #pragma unroll
    for (int dlt = 1; dlt < 16; dlt <<= 1)
      #pragma unroll
      for (int r = 0; r < 4; r++)
        rmax[r] = fmaxf(rmax[r], __shfl_xor(rmax[r], dlt, 64));

    // ---- online softmax update ----
    float mnew[4], fac[4], rsum[4];
    #pragma unroll
    for (int r = 0; r < 4; r++) {
      float mn = fmaxf(mrow[r], rmax[r]);
      fac[r] = exp2f((mrow[r] - mn) * L2E);
      mnew[r] = mn;
      mrow[r] = mn;
      rsum[r] = 0.f;
    }
    // P = exp(s - m): write bf16 to per-wave LDS (swizzled), accumulate row sums
    #pragma unroll
    for (int nc = 0; nc < 4; nc++) {
      #pragma unroll
      for (int r = 0; r < 4; r++) {
        float p = exp2f((s[nc][r] - mnew[r]) * L2E);
        rsum[r] += p;
        int prow = l4 * 4 + r;
        int pkey = nc * 16 + l15;
        int chunk = pkey >> 3;
        *(unsigned short*)(pbase + prow * 128 + ((chunk ^ (prow & 7)) << 4) + (pkey & 7) * 2) = f2bf(p);
      }
    }
    #pragma unroll
    for (int dlt = 1; dlt < 16; dlt <<= 1)
      #pragma unroll
      for (int r = 0; r < 4; r++)
        rsum[r] += __shfl_xor(rsum[r], dlt, 64);
    #pragma unroll
    for (int r = 0; r < 4; r++)
      lrow[r] = lrow[r] * fac[r] + rsum[r];
    #pragma unroll
    for (int onc = 0; onc < 4; onc++)
      #pragma unroll
      for (int r = 0; r < 4; r++)
        o[onc][r] *= fac[r];

    // ---- O += P V ----
    #pragma unroll
    for (int kk = 0; kk < 2; kk++) {
      int cc = kk * 4 + l4;
      bf16x8 pf = *(const bf16x8*)(pbase + l15 * 128 + ((cc ^ (l15 & 7)) << 4));
      #pragma unroll
      for (int onc = 0; onc < 4; onc++) {
        int dd = onc * 16 + l15;
        bf16x8 vf = *(const bf16x8*)(Vt + dd * 128 + ((cc ^ (dd & 7)) << 4));
        o[onc] = __builtin_amdgcn_mfma_f32_16x16x32_bf16(pf, vf, o[onc], 0, 0, 0);
      }
    }
    __syncthreads();
  }

  // ---- epilogue: att[b*2048+t][h*64+d] bf16 ----
  const int b = bh >> 4, h = bh & 15;
  #pragma unroll
  for (int onc = 0; onc < 4; onc++) {
    #pragma unroll
    for (int r = 0; r < 4; r++) {
      int t = qt * 64 + w * 16 + l4 * 4 + r;
      float val = o[onc][r] / lrow[r];
      att[((size_t)(b * 2048 + t)) * 1024 + h * 64 + onc * 16 + l15] = f2bf(val);
    }
  }
}

// ---------------- launch ----------------
extern "C" void kernel_launch(void* const* d_in, const int* in_sizes, int n_in,
                              void* d_out, int out_size, void* d_ws, size_t ws_size,
                              hipStream_t stream) {
  const float* x  = (const float*)d_in[0];   // [4,2048,1024]
  const float* Wa = (const float*)d_in[1];   // [1024,3072]
  const float* Wp = (const float*)d_in[2];   // [1024,1024]
  float* out = (float*)d_out;                // [4,2048,1024] fp32
  char* ws = (char*)d_ws;

  unsigned short* xb  = (unsigned short*)(ws);                 // 16 MB
  unsigned short* WaT = (unsigned short*)(ws + 16777216);      // 6 MB
  unsigned short* WpT = (unsigned short*)(ws + 23068672);      // 2 MB
  unsigned short* qb  = (unsigned short*)(ws + 25165824);      // 16 MB
  unsigned short* kb  = (unsigned short*)(ws + 41943040);      // 16 MB
  unsigned short* vb  = (unsigned short*)(ws + 58720256);      // 16 MB
  unsigned short* att = xb;                                    // reuse xb after GEMM1

  cvt_bf16_kernel<<<8192, 256, 0, stream>>>(x, xb, 8388608);
  dim3 tb(32, 8);
  transpose_cvt_kernel<<<dim3(96, 32), tb, 0, stream>>>(Wa, WaT, 1024, 3072);
  transpose_cvt_kernel<<<dim3(32, 32), tb, 0, stream>>>(Wp, WpT, 1024, 1024);

  // qkv = x @ W_attn, scattered into q/k/v head-major
  gemm_bf16<0><<<dim3(24, 64), 256, 0, stream>>>(xb, WaT, nullptr, 1024, qb, kb, vb, 3072);

  attn_kernel<<<dim3(32, 64), 256, 0, stream>>>(qb, kb, vb, att);

  // out = att @ W_proj
  gemm_bf16<1><<<dim3(8, 64), 256, 0, stream>>>(att, WpT, out, 1024, nullptr, nullptr, nullptr, 1024);
}

// Round 2
// 199.593 us; speedup vs baseline: 1.8429x; 1.8429x over previous
//
#include <hip/hip_runtime.h>

using bf16x8 = __attribute__((ext_vector_type(8))) __bf16;
using f32x4  = __attribute__((ext_vector_type(4))) float;
using f32x16 = __attribute__((ext_vector_type(16))) float;

__device__ __forceinline__ unsigned short f2bf(float f) {
  unsigned u = __builtin_bit_cast(unsigned, f);
  u += 0x7fffu + ((u >> 16) & 1u);
  return (unsigned short)(u >> 16);
}

__device__ __forceinline__ void gload_lds16(const void* g, void* l) {
  __builtin_amdgcn_global_load_lds((const __attribute__((address_space(1))) void*)g,
                                   (__attribute__((address_space(3))) void*)l, 16, 0, 0);
}

// ---------------- fp32 -> bf16 convert ----------------
__global__ void cvt_bf16_kernel(const float* __restrict__ in,
                                unsigned short* __restrict__ out, int n) {
  int i = (blockIdx.x * blockDim.x + threadIdx.x) * 4;
  if (i < n) {
    float4 f = *(const float4*)(in + i);
    ushort4 o;
    o.x = f2bf(f.x); o.y = f2bf(f.y); o.z = f2bf(f.z); o.w = f2bf(f.w);
    *(ushort4*)(out + i) = o;
  }
}

// ---------------- transpose + convert: W[K][N] fp32 -> WT[N][K] bf16 ----------------
__global__ void transpose_cvt_kernel(const float* __restrict__ W,
                                     unsigned short* __restrict__ WT, int K, int N) {
  __shared__ float tile[32][33];
  int n0 = blockIdx.x * 32, k0 = blockIdx.y * 32;
  int tx = threadIdx.x, ty = threadIdx.y;
  #pragma unroll
  for (int i = 0; i < 32; i += 8)
    tile[ty + i][tx] = W[(size_t)(k0 + ty + i) * N + (n0 + tx)];
  __syncthreads();
  #pragma unroll
  for (int i = 0; i < 32; i += 8)
    WT[(size_t)(n0 + ty + i) * K + (k0 + tx)] = f2bf(tile[tx][ty + i]);
}

// ---------------- bf16 GEMM: C[M][N] = A[M][K] * BT[N][K]^T ----------------
// BK=64, global_load_lds staging with source-side XOR swizzle (chunk ^ (row&7)).
// MODE 0: scatter bf16 into q/k/v head-major; MODE 1: fp32 store.
template <int MODE>
__global__ __launch_bounds__(256, 2)
void gemm_bf16(const unsigned short* __restrict__ A,
               const unsigned short* __restrict__ BT,
               float* __restrict__ Cout, int K,
               unsigned short* __restrict__ q_out,
               unsigned short* __restrict__ k_out,
               unsigned short* __restrict__ v_out, int N) {
  __shared__ alignas(16) char As[128 * 128];
  __shared__ alignas(16) char Bs[128 * 128];
  const int tid = threadIdx.x;
  const int lane = tid & 63, w = tid >> 6;
  const int wm = w >> 1, wn = w & 1;
  const int l15 = lane & 15, l4 = lane >> 4;
  const int bm = blockIdx.y, bn = blockIdx.x;

  f32x4 acc[4][4] = {};

  for (int kt = 0; kt < K; kt += 64) {
    #pragma unroll
    for (int i = 0; i < 4; i++) {
      int row = i * 32 + w * 8 + (lane >> 3);
      int sc = (lane & 7) ^ (row & 7);
      gload_lds16(A + (size_t)(bm * 128 + row) * K + kt + sc * 8, As + i * 4096 + w * 1024);
      gload_lds16(BT + (size_t)(bn * 128 + row) * K + kt + sc * 8, Bs + i * 4096 + w * 1024);
    }
    __syncthreads();
    #pragma unroll
    for (int kk = 0; kk < 2; kk++) {
      bf16x8 af[4], bfr[4];
      #pragma unroll
      for (int mc = 0; mc < 4; mc++) {
        int row = wm * 64 + mc * 16 + l15;
        af[mc] = *(const bf16x8*)(As + row * 128 + (((kk * 4 + l4) ^ (row & 7)) << 4));
      }
      #pragma unroll
      for (int nc = 0; nc < 4; nc++) {
        int row = wn * 64 + nc * 16 + l15;
        bfr[nc] = *(const bf16x8*)(Bs + row * 128 + (((kk * 4 + l4) ^ (row & 7)) << 4));
      }
      #pragma unroll
      for (int mc = 0; mc < 4; mc++)
        #pragma unroll
        for (int nc = 0; nc < 4; nc++)
          acc[mc][nc] = __builtin_amdgcn_mfma_f32_16x16x32_bf16(af[mc], bfr[nc], acc[mc][nc], 0, 0, 0);
    }
    __syncthreads();
  }

  #pragma unroll
  for (int mc = 0; mc < 4; mc++) {
    #pragma unroll
    for (int nc = 0; nc < 4; nc++) {
      #pragma unroll
      for (int r = 0; r < 4; r++) {
        int m = bm * 128 + wm * 64 + mc * 16 + l4 * 4 + r;
        int n = bn * 128 + wn * 64 + nc * 16 + l15;
        float val = acc[mc][nc][r];
        if (MODE == 0) {
          int b = m >> 11, t = m & 2047;
          int which = n >> 10, h = (n >> 6) & 15, d = n & 63;
          unsigned short* dst = (which == 0) ? q_out : (which == 1) ? k_out : v_out;
          dst[(((size_t)(b * 16 + h)) * 2048 + t) * 64 + d] = f2bf(val);
        } else {
          Cout[(size_t)m * N + n] = val;
        }
      }
    }
  }
}

// ---------------- flash attention, swapped-QK^T 32x32 structure ----------------
// Grid: 1024 1D blocks; qt = 15 - bid/64 (long blocks first), bh = bid%64.
// Block: 4 waves, QBLK=128 (32 q-rows/wave), KVBLK=64.
// S^T = mfma(K, Q): lane owns q = l&31 (cols); keys = kb*32 + (r&3)+8*(r>>2)+4*hi (rows).
// Softmax fully in-register; P repacked to PV A-frags via pack + shfl_xor(32).
__global__ __launch_bounds__(256, 3)
void attn_kernel(const unsigned short* __restrict__ q,
                 const unsigned short* __restrict__ k,
                 const unsigned short* __restrict__ v,
                 unsigned short* __restrict__ att) {
  __shared__ alignas(16) char Ks[64 * 128];   // [64 keys][64 d] bf16, chunk^(row&7) swizzle
  __shared__ alignas(16) char Vt[64 * 128];   // [64 d][64 keys] bf16 (transposed), swizzled

  const int bid = blockIdx.x;
  const int qt = 15 - (bid >> 6);
  const int bh = bid & 63;
  const int tid = threadIdx.x;
  const int lane = tid & 63, w = tid >> 6;
  const int l31 = lane & 31, hi = lane >> 5;
  const size_t base = (size_t)bh * 2048 * 64;

  // Q fragments (B-operand of mfma_32x32x16): lane holds Q[q=l31][ks*16 + hi*8 + j]
  bf16x8 qf[4];
  const int qrow = qt * 128 + w * 32 + l31;
  #pragma unroll
  for (int ks = 0; ks < 4; ks++)
    qf[ks] = *(const bf16x8*)(q + base + (size_t)qrow * 64 + ks * 16 + hi * 8);

  f32x16 o0 = {}, o1 = {};            // O[q=crow][d = db*32 + l31]
  float m = -1e30f, lsum = 0.f;
  const float SC = 0.125f, L2E = 1.44269504088896f;
  const int qmax = qt * 128 + w * 32 + 31;
  const int ntiles = 2 * qt + 2;

  for (int kt = 0; kt < ntiles; kt++) {
    // ---- stage K via global_load_lds, source chunk pre-swizzled ----
    #pragma unroll
    for (int i = 0; i < 2; i++) {
      int row = i * 32 + w * 8 + (lane >> 3);
      int sc = (lane & 7) ^ (row & 7);
      gload_lds16(k + base + (size_t)(kt * 64 + row) * 64 + sc * 8,
                  Ks + i * 4096 + w * 1024);
    }
    // ---- stage V transposed (reg-staged, swizzled) ----
    {
      int kp = tid & 31, dc = tid >> 5;
      const unsigned short* vr = v + base + (size_t)(kt * 64 + 2 * kp) * 64 + dc * 8;
      int4 va = *(const int4*)(vr);
      int4 vb = *(const int4*)(vr + 64);
      const unsigned short* pa_ = (const unsigned short*)&va;
      const unsigned short* pb_ = (const unsigned short*)&vb;
      #pragma unroll
      for (int j = 0; j < 8; j++) {
        int d = dc * 8 + j;
        unsigned int val = ((unsigned int)pb_[j] << 16) | pa_[j];
        *(unsigned int*)(Vt + d * 128 + (((kp >> 2) ^ (d & 7)) << 4) + (kp & 3) * 4) = val;
      }
    }
    __syncthreads();

    if (kt * 64 <= qmax) {
      // ---- S^T = K Q^T : 8 x mfma_32x32x16 ----
      f32x16 s0 = {}, s1 = {};
      #pragma unroll
      for (int ks = 0; ks < 4; ks++) {
        int c = ks * 2 + hi;
        bf16x8 k0 = *(const bf16x8*)(Ks + l31 * 128 + ((c ^ (l31 & 7)) << 4));
        bf16x8 k1 = *(const bf16x8*)(Ks + (32 + l31) * 128 + ((c ^ (l31 & 7)) << 4));
        s0 = __builtin_amdgcn_mfma_f32_32x32x16_bf16(k0, qf[ks], s0, 0, 0, 0);
        s1 = __builtin_amdgcn_mfma_f32_32x32x16_bf16(k1, qf[ks], s1, 0, 0, 0);
      }

      // ---- scale + causal mask + in-register row max ----
      const int kbase = kt * 64;
      float pmA = -1e30f, pmB = -1e30f;
      #pragma unroll
      for (int r = 0; r < 16; r++) {
        int crow = (r & 3) + 8 * (r >> 2) + 4 * hi;
        float v0 = s0[r] * SC; if (kbase + crow > qrow) v0 = -1e30f;
        float v1 = s1[r] * SC; if (kbase + 32 + crow > qrow) v1 = -1e30f;
        s0[r] = v0; s1[r] = v1;
        pmA = fmaxf(pmA, v0); pmB = fmaxf(pmB, v1);
      }
      float pm = fmaxf(pmA, pmB);
      pm = fmaxf(pm, __shfl_xor(pm, 32, 64));

      // ---- online softmax with deferred rescale (THR = 8 nats) ----
      if (!__all(pm <= m + 8.0f)) {
        float mn = fmaxf(m, pm);
        float fac = exp2f((m - mn) * L2E);
        m = mn; lsum *= fac;
        #pragma unroll
        for (int r = 0; r < 16; r++) {
          float fr = __shfl(fac, (r & 3) + 8 * (r >> 2) + 4 * hi, 64);
          o0[r] *= fr; o1[r] *= fr;
        }
      }
      float lsA = 0.f, lsB = 0.f;
      #pragma unroll
      for (int r = 0; r < 16; r++) {
        float p0 = exp2f((s0[r] - m) * L2E);
        float p1 = exp2f((s1[r] - m) * L2E);
        s0[r] = p0; s1[r] = p1;
        lsA += p0; lsB += p1;
      }
      lsum += lsA + lsB;

      // ---- repack P to bf16 PV A-frags (pack pairs + cross-half exchange) ----
      bf16x8 pa[4];
      #pragma unroll
      for (int kb = 0; kb < 2; kb++) {
        unsigned A0, A1, B0, B1, C0, C1, D0, D1;
        if (kb == 0) {
          A0 = (unsigned)f2bf(s0[1]) << 16 | f2bf(s0[0]);
          A1 = (unsigned)f2bf(s0[3]) << 16 | f2bf(s0[2]);
          B0 = (unsigned)f2bf(s0[5]) << 16 | f2bf(s0[4]);
          B1 = (unsigned)f2bf(s0[7]) << 16 | f2bf(s0[6]);
          C0 = (unsigned)f2bf(s0[9]) << 16 | f2bf(s0[8]);
          C1 = (unsigned)f2bf(s0[11]) << 16 | f2bf(s0[10]);
          D0 = (unsigned)f2bf(s0[13]) << 16 | f2bf(s0[12]);
          D1 = (unsigned)f2bf(s0[15]) << 16 | f2bf(s0[14]);
        } else {
          A0 = (unsigned)f2bf(s1[1]) << 16 | f2bf(s1[0]);
          A1 = (unsigned)f2bf(s1[3]) << 16 | f2bf(s1[2]);
          B0 = (unsigned)f2bf(s1[5]) << 16 | f2bf(s1[4]);
          B1 = (unsigned)f2bf(s1[7]) << 16 | f2bf(s1[6]);
          C0 = (unsigned)f2bf(s1[9]) << 16 | f2bf(s1[8]);
          C1 = (unsigned)f2bf(s1[11]) << 16 | f2bf(s1[10]);
          D0 = (unsigned)f2bf(s1[13]) << 16 | f2bf(s1[12]);
          D1 = (unsigned)f2bf(s1[15]) << 16 | f2bf(s1[14]);
        }
        unsigned tA0 = __shfl_xor((int)A0, 32, 64), tA1 = __shfl_xor((int)A1, 32, 64);
        unsigned tB0 = __shfl_xor((int)B0, 32, 64), tB1 = __shfl_xor((int)B1, 32, 64);
        unsigned tC0 = __shfl_xor((int)C0, 32, 64), tC1 = __shfl_xor((int)C1, 32, 64);
        unsigned tD0 = __shfl_xor((int)D0, 32, 64), tD1 = __shfl_xor((int)D1, 32, 64);
        uint4 f0, f1;
        f0.x = hi ? tB0 : A0;  f0.y = hi ? tB1 : A1;
        f0.z = hi ? B0 : tA0;  f0.w = hi ? B1 : tA1;
        f1.x = hi ? tD0 : C0;  f1.y = hi ? tD1 : C1;
        f1.z = hi ? D0 : tC0;  f1.w = hi ? D1 : tC1;
        pa[2 * kb]     = __builtin_bit_cast(bf16x8, f0);
        pa[2 * kb + 1] = __builtin_bit_cast(bf16x8, f1);
      }

      // ---- O += P V : 8 x mfma_32x32x16 ----
      #pragma unroll
      for (int ks = 0; ks < 4; ks++) {
        int c = ks * 2 + hi;
        int dr0 = l31, dr1 = 32 + l31;
        bf16x8 vf0 = *(const bf16x8*)(Vt + dr0 * 128 + ((c ^ (dr0 & 7)) << 4));
        bf16x8 vf1 = *(const bf16x8*)(Vt + dr1 * 128 + ((c ^ (dr1 & 7)) << 4));
        o0 = __builtin_amdgcn_mfma_f32_32x32x16_bf16(pa[ks], vf0, o0, 0, 0, 0);
        o1 = __builtin_amdgcn_mfma_f32_32x32x16_bf16(pa[ks], vf1, o1, 0, 0, 0);
      }
    }
    __syncthreads();
  }

  // ---- epilogue ----
  lsum += __shfl_xor(lsum, 32, 64);
  float linv = 1.0f / lsum;
  const int b_ = bh >> 4, h = bh & 15;
  #pragma unroll
  for (int r = 0; r < 16; r++) {
    int crow = (r & 3) + 8 * (r >> 2) + 4 * hi;
    float li = __shfl(linv, crow, 64);
    int t = qt * 128 + w * 32 + crow;
    size_t rb = ((size_t)(b_ * 2048 + t)) * 1024 + h * 64;
    att[rb + l31] = f2bf(o0[r] * li);
    att[rb + 32 + l31] = f2bf(o1[r] * li);
  }
}

// ---------------- launch ----------------
extern "C" void kernel_launch(void* const* d_in, const int* in_sizes, int n_in,
                              void* d_out, int out_size, void* d_ws, size_t ws_size,
                              hipStream_t stream) {
  const float* x  = (const float*)d_in[0];   // [4,2048,1024]
  const float* Wa = (const float*)d_in[1];   // [1024,3072]
  const float* Wp = (const float*)d_in[2];   // [1024,1024]
  float* out = (float*)d_out;                // [4,2048,1024] fp32
  char* ws = (char*)d_ws;

  unsigned short* xb  = (unsigned short*)(ws);                 // 16 MB
  unsigned short* WaT = (unsigned short*)(ws + 16777216);      // 6 MB
  unsigned short* WpT = (unsigned short*)(ws + 23068672);      // 2 MB
  unsigned short* qb  = (unsigned short*)(ws + 25165824);      // 16 MB
  unsigned short* kb  = (unsigned short*)(ws + 41943040);      // 16 MB
  unsigned short* vb  = (unsigned short*)(ws + 58720256);      // 16 MB
  unsigned short* att = xb;                                    // reuse xb after GEMM1

  cvt_bf16_kernel<<<8192, 256, 0, stream>>>(x, xb, 8388608);
  dim3 tb(32, 8);
  transpose_cvt_kernel<<<dim3(96, 32), tb, 0, stream>>>(Wa, WaT, 1024, 3072);
  transpose_cvt_kernel<<<dim3(32, 32), tb, 0, stream>>>(Wp, WpT, 1024, 1024);

  gemm_bf16<0><<<dim3(24, 64), 256, 0, stream>>>(xb, WaT, nullptr, 1024, qb, kb, vb, 3072);

  attn_kernel<<<1024, 256, 0, stream>>>(qb, kb, vb, att);

  gemm_bf16<1><<<dim3(8, 64), 256, 0, stream>>>(att, WpT, out, 1024, nullptr, nullptr, nullptr, 1024);
}

// Round 3
// 181.834 us; speedup vs baseline: 2.0229x; 1.0977x over previous
//
#include <hip/hip_runtime.h>

using bf16x8 = __attribute__((ext_vector_type(8))) __bf16;
using f32x4  = __attribute__((ext_vector_type(4))) float;
using f32x16 = __attribute__((ext_vector_type(16))) float;

__device__ __forceinline__ unsigned short f2bf(float f) {
  unsigned u = __builtin_bit_cast(unsigned, f);
  u += 0x7fffu + ((u >> 16) & 1u);
  return (unsigned short)(u >> 16);
}

__device__ __forceinline__ unsigned cvt_pk_bf16(float lo, float hi) {
  unsigned r;
  asm("v_cvt_pk_bf16_f32 %0, %1, %2" : "=v"(r) : "v"(lo), "v"(hi));
  return r;
}

// v_permlane32_swap_b32 D,S: D.lanes[32:63] <-> S.lanes[0:31].
// After: a = {a.lo-half, b.lo-half}, b = {a.hi-half, b.hi-half}.
__device__ __forceinline__ void permswap(unsigned &a, unsigned &b) {
  asm("v_permlane32_swap_b32 %0, %1" : "+v"(a), "+v"(b));
}

__device__ __forceinline__ void gload_lds16(const void* g, void* l) {
  __builtin_amdgcn_global_load_lds((const __attribute__((address_space(1))) void*)g,
                                   (__attribute__((address_space(3))) void*)l, 16, 0, 0);
}

// ---------------- fp32 -> bf16 convert ----------------
__global__ void cvt_bf16_kernel(const float* __restrict__ in,
                                unsigned short* __restrict__ out, int n) {
  int i = (blockIdx.x * blockDim.x + threadIdx.x) * 4;
  if (i < n) {
    float4 f = *(const float4*)(in + i);
    ushort4 o;
    o.x = f2bf(f.x); o.y = f2bf(f.y); o.z = f2bf(f.z); o.w = f2bf(f.w);
    *(ushort4*)(out + i) = o;
  }
}

// ---------------- transpose + convert: W[K][N] fp32 -> WT[N][K] bf16 ----------------
__global__ void transpose_cvt_kernel(const float* __restrict__ W,
                                     unsigned short* __restrict__ WT, int K, int N) {
  __shared__ float tile[32][33];
  int n0 = blockIdx.x * 32, k0 = blockIdx.y * 32;
  int tx = threadIdx.x, ty = threadIdx.y;
  #pragma unroll
  for (int i = 0; i < 32; i += 8)
    tile[ty + i][tx] = W[(size_t)(k0 + ty + i) * N + (n0 + tx)];
  __syncthreads();
  #pragma unroll
  for (int i = 0; i < 32; i += 8)
    WT[(size_t)(n0 + ty + i) * K + (k0 + tx)] = f2bf(tile[tx][ty + i]);
}

// ---------------- bf16 GEMM: C[M][N] = A[M][K] * BT[N][K]^T ----------------
template <int MODE>
__global__ __launch_bounds__(256, 2)
void gemm_bf16(const unsigned short* __restrict__ A,
               const unsigned short* __restrict__ BT,
               float* __restrict__ Cout, int K,
               unsigned short* __restrict__ q_out,
               unsigned short* __restrict__ k_out,
               unsigned short* __restrict__ v_out, int N) {
  __shared__ alignas(16) char As[128 * 128];
  __shared__ alignas(16) char Bs[128 * 128];
  const int tid = threadIdx.x;
  const int lane = tid & 63, w = tid >> 6;
  const int wm = w >> 1, wn = w & 1;
  const int l15 = lane & 15, l4 = lane >> 4;
  const int bm = blockIdx.y, bn = blockIdx.x;

  f32x4 acc[4][4] = {};

  for (int kt = 0; kt < K; kt += 64) {
    #pragma unroll
    for (int i = 0; i < 4; i++) {
      int row = i * 32 + w * 8 + (lane >> 3);
      int sc = (lane & 7) ^ (row & 7);
      gload_lds16(A + (size_t)(bm * 128 + row) * K + kt + sc * 8, As + i * 4096 + w * 1024);
      gload_lds16(BT + (size_t)(bn * 128 + row) * K + kt + sc * 8, Bs + i * 4096 + w * 1024);
    }
    __syncthreads();
    #pragma unroll
    for (int kk = 0; kk < 2; kk++) {
      bf16x8 af[4], bfr[4];
      #pragma unroll
      for (int mc = 0; mc < 4; mc++) {
        int row = wm * 64 + mc * 16 + l15;
        af[mc] = *(const bf16x8*)(As + row * 128 + (((kk * 4 + l4) ^ (row & 7)) << 4));
      }
      #pragma unroll
      for (int nc = 0; nc < 4; nc++) {
        int row = wn * 64 + nc * 16 + l15;
        bfr[nc] = *(const bf16x8*)(Bs + row * 128 + (((kk * 4 + l4) ^ (row & 7)) << 4));
      }
      #pragma unroll
      for (int mc = 0; mc < 4; mc++)
        #pragma unroll
        for (int nc = 0; nc < 4; nc++)
          acc[mc][nc] = __builtin_amdgcn_mfma_f32_16x16x32_bf16(af[mc], bfr[nc], acc[mc][nc], 0, 0, 0);
    }
    __syncthreads();
  }

  #pragma unroll
  for (int mc = 0; mc < 4; mc++) {
    #pragma unroll
    for (int nc = 0; nc < 4; nc++) {
      #pragma unroll
      for (int r = 0; r < 4; r++) {
        int m = bm * 128 + wm * 64 + mc * 16 + l4 * 4 + r;
        int n = bn * 128 + wn * 64 + nc * 16 + l15;
        float val = acc[mc][nc][r];
        if (MODE == 0) {
          int b = m >> 11, t = m & 2047;
          int which = n >> 10, h = (n >> 6) & 15, d = n & 63;
          unsigned short* dst = (which == 0) ? q_out : (which == 1) ? k_out : v_out;
          dst[(((size_t)(b * 16 + h)) * 2048 + t) * 64 + d] = f2bf(val);
        } else {
          Cout[(size_t)m * N + n] = val;
        }
      }
    }
  }
}

// Repack one 16-reg C-layout block (32 keys x q) into two PV A-frags.
__device__ __forceinline__ void repack_pa(const f32x16 s, bf16x8 &fl, bf16x8 &fh) {
  unsigned p01 = cvt_pk_bf16(s[0], s[1]);
  unsigned p23 = cvt_pk_bf16(s[2], s[3]);
  unsigned p45 = cvt_pk_bf16(s[4], s[5]);
  unsigned p67 = cvt_pk_bf16(s[6], s[7]);
  unsigned p89 = cvt_pk_bf16(s[8], s[9]);
  unsigned pAB = cvt_pk_bf16(s[10], s[11]);
  unsigned pCD = cvt_pk_bf16(s[12], s[13]);
  unsigned pEF = cvt_pk_bf16(s[14], s[15]);
  permswap(p01, p45);
  permswap(p23, p67);
  permswap(p89, pCD);
  permswap(pAB, pEF);
  uint4 f0, f1;
  f0.x = p01; f0.y = p23; f0.z = p45; f0.w = p67;
  f1.x = p89; f1.y = pAB; f1.z = pCD; f1.w = pEF;
  fl = __builtin_bit_cast(bf16x8, f0);
  fh = __builtin_bit_cast(bf16x8, f1);
}

// ---------------- flash attention, swapped-QK^T 32x32, in-register softmax ----------------
__global__ __launch_bounds__(256, 3)
void attn_kernel(const unsigned short* __restrict__ q,
                 const unsigned short* __restrict__ k,
                 const unsigned short* __restrict__ v,
                 unsigned short* __restrict__ att) {
  __shared__ alignas(16) char Ks[64 * 128];
  __shared__ alignas(16) char Vt[64 * 128];

  const int bid = blockIdx.x;
  const int qt = 15 - (bid >> 6);
  const int bh = bid & 63;
  const int tid = threadIdx.x;
  const int lane = tid & 63, w = tid >> 6;
  const int l31 = lane & 31, hi = lane >> 5;
  const size_t base = (size_t)bh * 2048 * 64;

  bf16x8 qf[4];
  const int qwb = qt * 128 + w * 32;
  const int qrow = qwb + l31;
  #pragma unroll
  for (int ks = 0; ks < 4; ks++)
    qf[ks] = *(const bf16x8*)(q + base + (size_t)qrow * 64 + ks * 16 + hi * 8);

  f32x16 o0 = {}, o1 = {}, lacc = {};
  float m = -1e30f;
  const float SCL2E = 0.18033688f;       // (1/8) * log2(e)
  const float RTHR = 44.3614f;           // 8 / SCL2E
  const int qmax = qwb + 31;
  const int ntiles = 2 * qt + 2;

  uint4 onesw;
  onesw.x = 0x3F803F80u; onesw.y = 0x3F803F80u; onesw.z = 0x3F803F80u; onesw.w = 0x3F803F80u;
  const bf16x8 onesv = __builtin_bit_cast(bf16x8, onesw);

  for (int kt = 0; kt < ntiles; kt++) {
    // ---- stage K via global_load_lds (source pre-swizzled) ----
    #pragma unroll
    for (int i = 0; i < 2; i++) {
      int row = i * 32 + w * 8 + (lane >> 3);
      int sc = (lane & 7) ^ (row & 7);
      gload_lds16(k + base + (size_t)(kt * 64 + row) * 64 + sc * 8,
                  Ks + i * 4096 + w * 1024);
    }
    // ---- stage V transposed (reg-staged, swizzled) ----
    {
      int kp = tid & 31, dc = tid >> 5;
      const unsigned short* vr = v + base + (size_t)(kt * 64 + 2 * kp) * 64 + dc * 8;
      int4 va = *(const int4*)(vr);
      int4 vb = *(const int4*)(vr + 64);
      const unsigned short* pa_ = (const unsigned short*)&va;
      const unsigned short* pb_ = (const unsigned short*)&vb;
      #pragma unroll
      for (int j = 0; j < 8; j++) {
        int d = dc * 8 + j;
        unsigned int val = ((unsigned int)pb_[j] << 16) | pa_[j];
        *(unsigned int*)(Vt + d * 128 + (((kp >> 2) ^ (d & 7)) << 4) + (kp & 3) * 4) = val;
      }
    }
    __syncthreads();

    if (kt * 64 <= qmax) {
      const int kbase = kt * 64;
      // ---- S^T = K Q^T : 8 x mfma_32x32x16 (raw scores) ----
      f32x16 s0 = {}, s1 = {};
      #pragma unroll
      for (int ks = 0; ks < 4; ks++) {
        int c = ks * 2 + hi;
        bf16x8 k0 = *(const bf16x8*)(Ks + l31 * 128 + ((c ^ (l31 & 7)) << 4));
        bf16x8 k1 = *(const bf16x8*)(Ks + (32 + l31) * 128 + ((c ^ (l31 & 7)) << 4));
        s0 = __builtin_amdgcn_mfma_f32_32x32x16_bf16(k0, qf[ks], s0, 0, 0, 0);
        s1 = __builtin_amdgcn_mfma_f32_32x32x16_bf16(k1, qf[ks], s1, 0, 0, 0);
      }

      // ---- causal mask (diagonal tiles only, wave-uniform test) ----
      if (kbase + 63 > qwb) {
        #pragma unroll
        for (int r = 0; r < 16; r++) {
          int crow = (r & 3) + 8 * (r >> 2) + 4 * hi;
          if (kbase + crow > qrow) s0[r] = -1e30f;
          if (kbase + 32 + crow > qrow) s1[r] = -1e30f;
        }
      }

      // ---- row max (raw domain) ----
      float pm = -1e30f;
      #pragma unroll
      for (int r = 0; r < 16; r++)
        pm = fmaxf(pm, fmaxf(s0[r], s1[r]));
      pm = fmaxf(pm, __shfl_xor(pm, 32, 64));

      // ---- deferred rescale (threshold 8 in exp2 domain) ----
      if (!__all(pm <= m + RTHR)) {
        float mn = fmaxf(m, pm);
        float fac = exp2f((m - mn) * SCL2E);
        m = mn;
        #pragma unroll
        for (int r = 0; r < 16; r++) {
          float fr = __shfl(fac, (r & 3) + 8 * (r >> 2) + 4 * hi, 64);
          o0[r] *= fr; o1[r] *= fr; lacc[r] *= fr;
        }
      }

      // ---- P = exp2((s - m) * SCL2E), in place ----
      const float mc = -m * SCL2E;
      #pragma unroll
      for (int r = 0; r < 16; r++) {
        s0[r] = exp2f(__builtin_fmaf(s0[r], SCL2E, mc));
        s1[r] = exp2f(__builtin_fmaf(s1[r], SCL2E, mc));
      }

      // ---- repack to PV A-frags (cvt_pk + permlane32_swap) ----
      bf16x8 pa[4];
      repack_pa(s0, pa[0], pa[1]);
      repack_pa(s1, pa[2], pa[3]);

      // ---- O += P V ; row-sums via ones-column MFMA ----
      #pragma unroll
      for (int ks = 0; ks < 4; ks++) {
        int c = ks * 2 + hi;
        bf16x8 vf0 = *(const bf16x8*)(Vt + l31 * 128 + ((c ^ (l31 & 7)) << 4));
        bf16x8 vf1 = *(const bf16x8*)(Vt + (32 + l31) * 128 + ((c ^ (l31 & 7)) << 4));
        o0 = __builtin_amdgcn_mfma_f32_32x32x16_bf16(pa[ks], vf0, o0, 0, 0, 0);
        o1 = __builtin_amdgcn_mfma_f32_32x32x16_bf16(pa[ks], vf1, o1, 0, 0, 0);
        lacc = __builtin_amdgcn_mfma_f32_32x32x16_bf16(pa[ks], onesv, lacc, 0, 0, 0);
      }
    }
    __syncthreads();
  }

  // ---- epilogue: lacc[r] holds the row sum for q=crow (uniform across cols) ----
  const int b_ = bh >> 4, h = bh & 15;
  #pragma unroll
  for (int r = 0; r < 16; r++) {
    int crow = (r & 3) + 8 * (r >> 2) + 4 * hi;
    float li = 1.0f / lacc[r];
    int t = qt * 128 + w * 32 + crow;
    size_t rb = ((size_t)(b_ * 2048 + t)) * 1024 + h * 64;
    att[rb + l31] = f2bf(o0[r] * li);
    att[rb + 32 + l31] = f2bf(o1[r] * li);
  }
}

// ---------------- launch ----------------
extern "C" void kernel_launch(void* const* d_in, const int* in_sizes, int n_in,
                              void* d_out, int out_size, void* d_ws, size_t ws_size,
                              hipStream_t stream) {
  const float* x  = (const float*)d_in[0];   // [4,2048,1024]
  const float* Wa = (const float*)d_in[1];   // [1024,3072]
  const float* Wp = (const float*)d_in[2];   // [1024,1024]
  float* out = (float*)d_out;                // [4,2048,1024] fp32
  char* ws = (char*)d_ws;

  unsigned short* xb  = (unsigned short*)(ws);                 // 16 MB
  unsigned short* WaT = (unsigned short*)(ws + 16777216);      // 6 MB
  unsigned short* WpT = (unsigned short*)(ws + 23068672);      // 2 MB
  unsigned short* qb  = (unsigned short*)(ws + 25165824);      // 16 MB
  unsigned short* kb  = (unsigned short*)(ws + 41943040);      // 16 MB
  unsigned short* vb  = (unsigned short*)(ws + 58720256);      // 16 MB
  unsigned short* att = xb;                                    // reuse xb after GEMM1

  cvt_bf16_kernel<<<8192, 256, 0, stream>>>(x, xb, 8388608);
  dim3 tb(32, 8);
  transpose_cvt_kernel<<<dim3(96, 32), tb, 0, stream>>>(Wa, WaT, 1024, 3072);
  transpose_cvt_kernel<<<dim3(32, 32), tb, 0, stream>>>(Wp, WpT, 1024, 1024);

  gemm_bf16<0><<<dim3(24, 64), 256, 0, stream>>>(xb, WaT, nullptr, 1024, qb, kb, vb, 3072);

  attn_kernel<<<1024, 256, 0, stream>>>(qb, kb, vb, att);

  gemm_bf16<1><<<dim3(8, 64), 256, 0, stream>>>(att, WpT, out, 1024, nullptr, nullptr, nullptr, 1024);
}